// Round 1
// baseline (307.598 us; speedup 1.0000x reference)
//
#include <hip/hip_runtime.h>
#include <hip/hip_bf16.h>

// Problem constants (reference: F=26, D=128, B=16384, rows = F+1 = 27)
constexpr int kRows  = 27;
constexpr int kD     = 128;
constexpr int kPairs = 351;   // 27*26/2
constexpr int kNB    = 4;     // batches per block = waves per block (256 threads)

typedef __attribute__((ext_vector_type(8))) short bf16x8;   // 8 bf16 = 4 VGPRs (MFMA A/B fragment)
typedef __attribute__((ext_vector_type(4))) float f32x4;    // MFMA 16x16 accumulator

// fp32 -> bf16 RNE via the HIP intrinsic; compiler emits v_cvt_pk_bf16_f32 pairs
// (m240: compiler-generated conversion beats hand-written cvt_pk asm).
__device__ __forceinline__ short bfs(float x) {
    union { __hip_bfloat16 h; short s; } u;
    u.h = __float2bfloat16(x);
    return u.s;
}

__device__ __forceinline__ bf16x8 pack8(float4 a, float4 b) {
    bf16x8 r;
    r[0] = bfs(a.x); r[1] = bfs(a.y); r[2] = bfs(a.z); r[3] = bfs(a.w);
    r[4] = bfs(b.x); r[5] = bfs(b.y); r[6] = bfs(b.z); r[7] = bfs(b.w);
    return r;
}

__device__ __forceinline__ int triu_idx(int i, int j) {
    // row-major strict upper triangle of 27x27: k = i*(53-i)/2 + (j-i-1)
    return (i * (53 - i)) / 2 + (j - i - 1);
}

// Structural redesign vs previous version: no staging LDS, no __syncthreads, no
// pad-row zero-fill. Each wave owns one batch and loads its MFMA fragments
// DIRECTLY from global (each input byte read exactly once; adjacent instruction
// pairs fully consume every 64B line). LDS is only a 352-float/wave bounce
// buffer to turn the scattered triu stores into coalesced dword stores.
__global__ __launch_bounds__(256, 4) void interact_kernel(
    const float* __restrict__ sparse_x,   // [B][26][128] fp32
    const float* __restrict__ dense_x,    // [B][128] fp32
    float* __restrict__ out)              // [B][351] fp32
{
    __shared__ float obuf[kNB][kPairs + 1];   // 4 * 352 * 4 B = 5632 B
    const int t    = threadIdx.x;
    const int wave = t >> 6;
    const int lane = t & 63;
    const int m    = lane & 15;   // fragment row (M/N index)
    const int quad = lane >> 4;   // k-group
    const int batch = blockIdx.x * kNB + wave;

    const float* sb = sparse_x + (size_t)batch * (26 * kD);
    const int c0 = quad * 8;      // fragment k-offset within a 32-wide chunk

    // ---- Issue all global loads up front (16 float4/lane outstanding).
    // a0: rows 0-15 (always sparse). Lane reads X[m][k*32 + quad*8 .. +8).
    float4 f0[8];
    const float* p0 = sb + m * kD + c0;
    #pragma unroll
    for (int k = 0; k < 4; ++k) {
        f0[2 * k]     = *reinterpret_cast<const float4*>(p0 + k * 32);
        f0[2 * k + 1] = *reinterpret_cast<const float4*>(p0 + k * 32 + 4);
    }
    // a1: row 16+m -> sparse rows 16-25, dense row at 26, zero for 27-31.
    // (Garbage/zero pad rows only produce C entries that are never stored:
    //  MFMA D[i][j] depends solely on A row i / B row j.)
    float4 f1[8];
    const int r = 16 + m;
    if (r < kRows) {
        const float* p1 = (r < 26 ? sb + r * kD
                                  : dense_x + (size_t)batch * kD) + c0;
        #pragma unroll
        for (int k = 0; k < 4; ++k) {
            f1[2 * k]     = *reinterpret_cast<const float4*>(p1 + k * 32);
            f1[2 * k + 1] = *reinterpret_cast<const float4*>(p1 + k * 32 + 4);
        }
    } else {
        const float4 z = {0.f, 0.f, 0.f, 0.f};
        #pragma unroll
        for (int k = 0; k < 8; ++k) f1[k] = z;
    }

    // ---- Convert + MFMA per k-chunk (one a0/a1 fragment live at a time;
    // later chunks' converts overlap the still-in-flight loads via vmcnt(N)).
    f32x4 c00 = {0.f, 0.f, 0.f, 0.f};
    f32x4 c01 = {0.f, 0.f, 0.f, 0.f};
    f32x4 c11 = {0.f, 0.f, 0.f, 0.f};
    #pragma unroll
    for (int k = 0; k < 4; ++k) {
        bf16x8 a0 = pack8(f0[2 * k], f0[2 * k + 1]);
        bf16x8 a1 = pack8(f1[2 * k], f1[2 * k + 1]);
        c00 = __builtin_amdgcn_mfma_f32_16x16x32_bf16(a0, a0, c00, 0, 0, 0);
        c01 = __builtin_amdgcn_mfma_f32_16x16x32_bf16(a0, a1, c01, 0, 0, 0);
        c11 = __builtin_amdgcn_mfma_f32_16x16x32_bf16(a1, a1, c11, 0, 0, 0);
    }

    // ---- Epilogue: C/D layout col = lane&15, row = quad*4 + reg [m89/m91].
    // Scatter into per-wave LDS (covers all 351 slots exactly once), then
    // coalesced dword copy to global. Wave-private buffer: no __syncthreads
    // needed; compiler inserts the lgkmcnt wait for the LDS RAW dependency.
    float* ob = obuf[wave];
    const int j = m;
    #pragma unroll
    for (int rr = 0; rr < 4; ++rr) {
        const int i = quad * 4 + rr;
        if (i < j)                        ob[triu_idx(i, j)]           = c00[rr]; // 120 pairs
        if (16 + j < kRows)               ob[triu_idx(i, 16 + j)]      = c01[rr]; // 176 pairs
        if (i < j && 16 + j < kRows)      ob[triu_idx(16 + i, 16 + j)] = c11[rr]; //  55 pairs
    }
    float* og = out + (size_t)batch * kPairs;
    for (int e = lane; e < kPairs; e += 64) og[e] = ob[e];
}

extern "C" void kernel_launch(void* const* d_in, const int* in_sizes, int n_in,
                              void* d_out, int out_size, void* d_ws, size_t ws_size,
                              hipStream_t stream) {
    const float* sparse_x = (const float*)d_in[0];
    const float* dense_x  = (const float*)d_in[1];
    float* out = (float*)d_out;
    const int B = in_sizes[1] / kD;             // 16384
    interact_kernel<<<B / kNB, 256, 0, stream>>>(sparse_x, dense_x, out);
}